// Round 1
// baseline (1616.297 us; speedup 1.0000x reference)
//
#include <hip/hip_runtime.h>

typedef __bf16 bf16x8 __attribute__((ext_vector_type(8)));
typedef __bf16 bf16x4 __attribute__((ext_vector_type(4)));
typedef float  f32x4  __attribute__((ext_vector_type(4)));

#define CIN 320
// LDS layout (bytes): gather 96*256 | edge 96*128 | self 8*256
#define GATHER_OFF 0
#define EDGE_OFF   24576
#define SELF_OFF   36864
#define SMEM_BYTES 38912

// async 16B global->LDS DMA; LDS dest is wave-uniform base + lane*16
#define GLOAD_LDS16(gsrc, ldst)                                              \
    __builtin_amdgcn_global_load_lds(                                        \
        (__attribute__((address_space(1))) void*)(void*)(gsrc),              \
        (__attribute__((address_space(3))) void*)(ldst), 16, 0, 0)

// ---- runtime dtype detection (one wave): flags[0]=fp32 inputs, flags[1]=int64 idx
__global__ void detect_kernel(const unsigned short* __restrict__ atom_h,
                              const unsigned* __restrict__ idx_w, int* __restrict__ flags)
{
    const int lane = threadIdx.x;   // 64
    int f32 = 0;
    for (int i = lane; i < 256; i += 64) {
        const int e = (atom_h[i] >> 7) & 0xFF;   // bf16-exponent view of each halfword
        if (e >= 134) f32 = 1;                   // |x|>=128 impossible for N(0,1) bf16
    }
    const unsigned long long m32 = __ballot(f32);
    const int hi = (idx_w[2 * lane + 1] != 0) ? 1 : 0;
    const unsigned long long mhi = __ballot(hi); // int64 nonneg < 1e5 -> high dwords 0
    if (lane == 0) { flags[0] = m32 ? 1 : 0; flags[1] = mhi ? 0 : 1; }
}

// ---- canonicalize float tensor to bf16 in ws (cvt if fp32, copy if already bf16)
__global__ __launch_bounds__(256) void convert_bf16(const void* __restrict__ src,
    __bf16* __restrict__ dst, long n8, const int* __restrict__ flags)
{
    const long t = (long)blockIdx.x * 256 + threadIdx.x;
    if (t >= n8) return;
    const long i = t * 8;
    if (flags[0]) {
        const float* s = (const float*)src;
        bf16x8 o;
#pragma unroll
        for (int j = 0; j < 8; ++j) o[j] = (__bf16)s[i + j];
        *(bf16x8*)&dst[i] = o;
    } else {
        *(uint4*)&dst[i] = *(const uint4*)((const char*)src + i * 2);
    }
}

// MODE 0 = stats only, 1 = stats + store packed gated fragments, 2 = apply (recompute)
// 512 threads = 8 waves; wave wv owns filter cols [wv*16,wv*16+16) + core cols +128.
template<int MODE>
__global__ __launch_bounds__(512, 4) void gemm_conv(
    const __bf16* __restrict__ atomb, const void* __restrict__ nbrp,
    const void* __restrict__ idxp, const __bf16* __restrict__ Wb,
    const int* __restrict__ flags,
    float* __restrict__ stats1, const float* __restrict__ coef1,
    __bf16* __restrict__ gws, float* __restrict__ nsum)
{
    __shared__ __align__(16) char smem[SMEM_BYTES];

    const int tid = threadIdx.x;
    const int blk = blockIdx.x;
    const long rowbase = (long)blk * 96;
    const int  n0 = blk * 8;
    const int  isf32 = flags[0];
    const int  isi64 = flags[1];

    const int lane = tid & 63;
    const int wv   = tid >> 6;
    const int quad = lane >> 4;
    const int lrow = lane & 15;

    // ---------- async staging ----------
    // self rows deduplicated: 8 rows x 256B, linear (reads broadcast per atom)
    if (wv < 2) {
        const int row = wv * 4 + (lane >> 4);
        GLOAD_LDS16(atomb + (long)(n0 + row) * 128 + (lane & 15) * 8,
                    smem + SELF_OFF + wv * 1024);
    }
    // gather rows: 24 instrs x 4 rows; source pre-swizzled so linear LDS dest
    // yields conflict-free swizzled reads: chunk c of row r lives at (c^(r&7))*16
    long jrow[3]; int grow[3];
#pragma unroll
    for (int i = 0; i < 3; ++i) {
        const int t = wv + i * 8;
        grow[i] = 4 * t + (lane >> 4);
        jrow[i] = isi64 ? (long)((const long long*)idxp)[rowbase + grow[i]]
                        : (long)((const int*)idxp)[rowbase + grow[i]];
    }
#pragma unroll
    for (int i = 0; i < 3; ++i) {
        const int t = wv + i * 8;
        const int chunk = ((lane & 15) << 4) ^ ((grow[i] & 7) << 4);  // byte in 256B row
        GLOAD_LDS16(atomb + jrow[i] * 128 + (chunk >> 1),
                    smem + GATHER_OFF + t * 1024);
    }
    // edge rows (64 feats): bf16 input -> DMA w/ pre-swizzled source; fp32 -> cvt+swizzled write
    if (isf32) {
        const float* nf = (const float*)nbrp;
#pragma unroll
        for (int rnd = 0; rnd < 2; ++rnd) {
            const int task = tid + rnd * 512;
            if (task < 768) {
                const int c = task & 7, row = task >> 3;
                const float* sp = &nf[(rowbase + row) * 64 + c * 8];
                f32x4 v0 = *(const f32x4*)sp;
                f32x4 v1 = *(const f32x4*)(sp + 4);
                bf16x8 o;
#pragma unroll
                for (int j = 0; j < 4; ++j) { o[j] = (__bf16)v0[j]; o[j + 4] = (__bf16)v1[j]; }
                *(bf16x8*)(smem + EDGE_OFF + row * 128 + ((c ^ (row & 7)) << 4)) = o;
            }
        }
    } else {
        const __bf16* nb = (const __bf16*)nbrp;
#pragma unroll
        for (int i = 0; i < 2; ++i) {
            const int t = wv + i * 8;
            if (t < 12) {
                const int row = 8 * t + (lane >> 3);
                const int c = lane & 7;
                const int chunk = (c << 4) ^ ((row & 7) << 4);
                GLOAD_LDS16(nb + (rowbase + row) * 64 + (chunk >> 1),
                            smem + EDGE_OFF + t * 1024);
            }
        }
    }
    __syncthreads();

    // ---------- MFMA ----------
    const int cF = wv * 16 + lrow;                       // 0..127
    const __bf16* wpF = Wb + (long)cF * CIN + quad * 8;
    const __bf16* wpC = Wb + (long)(128 + cF) * CIN + quad * 8;

    int arow[6], aatom[6];
#pragma unroll
    for (int rt = 0; rt < 6; ++rt) {
        arow[rt]  = rt * 16 + lrow;
        aatom[rt] = (arow[rt] * 171) >> 11;              // == row/12 for row<96
    }

    f32x4 acc[6][2] = {};
    bf16x8 bF = *(const bf16x8*)wpF;
    bf16x8 bC = *(const bf16x8*)wpC;
    bf16x8 bFn, bCn;

#pragma unroll
    for (int kk = 0; kk < 10; ++kk) {
        if (kk < 9) {
            bFn = *(const bf16x8*)(wpF + (kk + 1) * 32);
            bCn = *(const bf16x8*)(wpC + (kk + 1) * 32);
        }
#pragma unroll
        for (int rt = 0; rt < 6; ++rt) {
            int addr;
            if (kk < 4)
                addr = SELF_OFF + aatom[rt] * 256 + kk * 64 + quad * 16;
            else if (kk < 8)
                addr = GATHER_OFF + arow[rt] * 256 + ((((kk - 4) * 4 + quad) ^ (arow[rt] & 7)) << 4);
            else
                addr = EDGE_OFF + arow[rt] * 128 + ((((kk - 8) * 4 + quad) ^ (arow[rt] & 7)) << 4);
            const bf16x8 afrag = *(const bf16x8*)(smem + addr);
            acc[rt][0] = __builtin_amdgcn_mfma_f32_16x16x32_bf16(afrag, bF, acc[rt][0], 0, 0, 0);
            acc[rt][1] = __builtin_amdgcn_mfma_f32_16x16x32_bf16(afrag, bC, acc[rt][1], 0, 0, 0);
        }
        if (kk < 9) { bF = bFn; bC = bCn; }
    }

    if (MODE <= 1) {
        float* st = stats1 + (blk & 63) * 512;
#pragma unroll
        for (int p = 0; p < 2; ++p) {
            float s = 0.f, ss = 0.f;
#pragma unroll
            for (int rt = 0; rt < 6; ++rt)
#pragma unroll
                for (int r = 0; r < 4; ++r) {
                    const float v = acc[rt][p][r];
                    s += v; ss += v * v;
                }
            s += __shfl_xor(s, 16); ss += __shfl_xor(ss, 16);
            s += __shfl_xor(s, 32); ss += __shfl_xor(ss, 32);
            if (quad == 0) {
                atomicAdd(&st[p * 128 + cF], s);
                atomicAdd(&st[256 + p * 128 + cF], ss);
            }
        }
        if (MODE == 1) {
            // store fragments directly: word = pack(bf16 filt, bf16 core)
            // layout: [blk][rt(6)][tid(512)][16B]  -> 48KB/block, fully coalesced
            char* dst = (char*)gws + (long)blk * 49152;
#pragma unroll
            for (int rt = 0; rt < 6; ++rt) {
                unsigned u[4];
#pragma unroll
                for (int r = 0; r < 4; ++r) {
                    const unsigned short fb =
                        __builtin_bit_cast(unsigned short, (__bf16)acc[rt][0][r]);
                    const unsigned short cb =
                        __builtin_bit_cast(unsigned short, (__bf16)acc[rt][1][r]);
                    u[r] = (unsigned)fb | ((unsigned)cb << 16);
                }
                *(uint4*)(dst + rt * 8192 + tid * 16) = *(const uint4*)u;
            }
        }
    } else {
        // MODE 2: bn1 affine + sigmoid(filter)*relu(core), reduce over m in LDS
        __syncthreads();                      // done reading staged A
        float* sumbuf = (float*)smem;         // 8 atoms x 128 ch
        sumbuf[tid] = 0.f; sumbuf[tid + 512] = 0.f;
        __syncthreads();
        const float aF = coef1[cF],       bFc = coef1[256 + cF];
        const float aC = coef1[128 + cF], bCc = coef1[384 + cF];
#pragma unroll
        for (int rt = 0; rt < 6; ++rt)
#pragma unroll
            for (int r = 0; r < 4; ++r) {
                const int row  = rt * 16 + quad * 4 + r;
                const int atom = (row * 171) >> 11;
                const float gF = aF * acc[rt][0][r] + bFc;
                const float gC = aC * acc[rt][1][r] + bCc;
                const float val = (1.f / (1.f + __expf(-gF))) * fmaxf(gC, 0.f);
                atomicAdd(&sumbuf[atom * 128 + cF], val);
            }
        __syncthreads();
        nsum[(long)n0 * 128 + tid]       = sumbuf[tid];
        nsum[(long)n0 * 128 + 512 + tid] = sumbuf[tid + 512];
    }
}

__global__ void reduce_bn1(const float* __restrict__ stats1, const void* __restrict__ gamma,
                           const void* __restrict__ beta, float* __restrict__ coef1,
                           const int* __restrict__ flags)
{
    const int c = threadIdx.x;  // 256
    const int isf32 = flags[0];
    float s = 0.f, ss = 0.f;
    for (int b = 0; b < 64; ++b) { s += stats1[b * 512 + c]; ss += stats1[b * 512 + 256 + c]; }
    const float inv  = 1.f / 1200000.f;
    const float mean = s * inv;
    const float var  = ss * inv - mean * mean;
    const float g  = isf32 ? ((const float*)gamma)[c] : (float)((const __bf16*)gamma)[c];
    const float bb = isf32 ? ((const float*)beta)[c]  : (float)((const __bf16*)beta)[c];
    const float A = g * rsqrtf(var + 1e-5f);
    coef1[c]       = A;
    coef1[256 + c] = bb - A * mean;   // linear bias b cancels in BN1 (mean-subtracted)
}

// Path A: read fragment-layout gated, bn1 affine + gate + M-sum via LDS reduce
__global__ __launch_bounds__(512) void apply_gated(const __bf16* __restrict__ g,
    const float* __restrict__ coef1, float* __restrict__ nsum)
{
    __shared__ float sumbuf[1024];
    const int tid  = threadIdx.x;
    const int blk  = blockIdx.x;
    const int lane = tid & 63;
    const int wv   = tid >> 6;
    const int quad = lane >> 4;
    const int lrow = lane & 15;
    const int cF   = wv * 16 + lrow;
    sumbuf[tid] = 0.f; sumbuf[tid + 512] = 0.f;
    __syncthreads();
    const float aF = coef1[cF],       bF = coef1[256 + cF];
    const float aC = coef1[128 + cF], bC = coef1[384 + cF];
    const char* src = (const char*)g + (long)blk * 49152;
#pragma unroll
    for (int rt = 0; rt < 6; ++rt) {
        const uint4 w = *(const uint4*)(src + rt * 8192 + tid * 16);
        const unsigned u[4] = {w.x, w.y, w.z, w.w};
#pragma unroll
        for (int r = 0; r < 4; ++r) {
            const int row  = rt * 16 + quad * 4 + r;
            const int atom = (row * 171) >> 11;
            const float gF = aF * (float)__builtin_bit_cast(__bf16, (unsigned short)(u[r] & 0xFFFFu)) + bF;
            const float gC = aC * (float)__builtin_bit_cast(__bf16, (unsigned short)(u[r] >> 16)) + bC;
            const float val = (1.f / (1.f + __expf(-gF))) * fmaxf(gC, 0.f);
            atomicAdd(&sumbuf[atom * 128 + cF], val);
        }
    }
    __syncthreads();
    const long n0 = (long)blk * 8;
    nsum[n0 * 128 + tid]       = sumbuf[tid];
    nsum[n0 * 128 + 512 + tid] = sumbuf[tid + 512];
}

__global__ __launch_bounds__(256) void bn2_stats(const float* __restrict__ nsum,
                                                 float* __restrict__ stats2)
{
    __shared__ float ls[256], lss[256];
    const int tid = threadIdx.x;
    float s = 0.f, ss = 0.f;
    const long stride = (long)gridDim.x * 256;   // multiple of 128
    for (long i = (long)blockIdx.x * 256 + tid; i < 12800000L; i += stride) {
        const float v = nsum[i]; s += v; ss += v * v;
    }
    ls[tid] = s; lss[tid] = ss;
    __syncthreads();
    if (tid < 128) {
        atomicAdd(&stats2[tid],       ls[tid] + ls[tid + 128]);
        atomicAdd(&stats2[128 + tid], lss[tid] + lss[tid + 128]);
    }
}

__global__ void reduce_bn2(const float* __restrict__ stats2, const void* __restrict__ gamma,
                           const void* __restrict__ beta, float* __restrict__ coef2,
                           const int* __restrict__ flags)
{
    const int c = threadIdx.x;  // 128
    const int isf32 = flags[0];
    const float inv  = 1.f / 100000.f;
    const float mean = stats2[c] * inv;
    const float var  = stats2[128 + c] * inv - mean * mean;
    const float g  = isf32 ? ((const float*)gamma)[c] : (float)((const __bf16*)gamma)[c];
    const float bb = isf32 ? ((const float*)beta)[c]  : (float)((const __bf16*)beta)[c];
    const float A = g * rsqrtf(var + 1e-5f);
    coef2[c]       = A;
    coef2[128 + c] = bb - A * mean;
}

__global__ __launch_bounds__(256) void final_out(const __bf16* __restrict__ atomb,
    const float* __restrict__ nsum, const float* __restrict__ coef2,
    void* __restrict__ outp, const int* __restrict__ flags)
{
    const long i = ((long)blockIdx.x * 256 + threadIdx.x) * 8;   // 6250*256*8 = 12.8M exact
    const int f0 = (int)(i & 127);
    bf16x8 a  = *(const bf16x8*)&atomb[i];
    f32x4  u0 = *(const f32x4*)&nsum[i];
    f32x4  u1 = *(const f32x4*)&nsum[i + 4];
    float v[8];
#pragma unroll
    for (int j = 0; j < 8; ++j) {
        const float A  = coef2[f0 + j];
        const float B  = coef2[128 + f0 + j];
        const float ns = (j < 4) ? u0[j] : u1[j - 4];
        v[j] = fmaxf((float)a[j] + A * ns + B, 0.f);
    }
    if (flags[0]) {
        float* o = (float*)outp;
        f32x4 w0 = {v[0], v[1], v[2], v[3]}, w1 = {v[4], v[5], v[6], v[7]};
        *(f32x4*)&o[i]     = w0;
        *(f32x4*)&o[i + 4] = w1;
    } else {
        __bf16* o = (__bf16*)outp;
        bf16x8 w;
#pragma unroll
        for (int j = 0; j < 8; ++j) w[j] = (__bf16)v[j];
        *(bf16x8*)&o[i] = w;
    }
}

extern "C" void kernel_launch(void* const* d_in, const int* in_sizes, int n_in,
                              void* d_out, int out_size, void* d_ws, size_t ws_size,
                              hipStream_t stream)
{
    const void* atom = d_in[0];
    const void* nbr  = d_in[1];
    const void* idxp = d_in[2];
    const void* W    = d_in[3];
    // d_in[4] = linear bias: cancels exactly inside BN1, unused
    const void* g1   = d_in[5];
    const void* b1   = d_in[6];
    const void* g2   = d_in[7];
    const void* b2   = d_in[8];

    char* ws = (char*)d_ws;
    int*    flags  = (int*)ws;                       // 16 B
    float*  stats1 = (float*)(ws + 1024);            // 64*512*4 = 131072
    float*  coef1  = (float*)(ws + 132096);          // 2048
    float*  stats2 = (float*)(ws + 134144);          // 1024
    float*  coef2  = (float*)(ws + 135168);          // 1024
    __bf16* atomb  = (__bf16*)(ws + 136192);         // 12.8M bf16 = 25,600,000
    __bf16* Wb     = (__bf16*)(ws + 25736192);       // 81920 bf16 = 163,840
    float*  nsum   = (float*)(ws + 25900032);        // 100000*128*4 = 51,200,000
    __bf16* gws    = (__bf16*)(ws + 77100032);       // 12500*49152 = 614,400,000

    const size_t need_big = 77100032UL + 614400000UL;

    hipMemsetAsync(ws, 0, 136192, stream);           // zero flags + stats (ws poisoned 0xAA)
    detect_kernel<<<1, 64, 0, stream>>>((const unsigned short*)atom, (const unsigned*)idxp, flags);
    convert_bf16<<<6250, 256, 0, stream>>>(atom, atomb, 1600000L, flags);
    convert_bf16<<<40, 256, 0, stream>>>(W, Wb, 10240L, flags);

    if (ws_size >= need_big) {
        gemm_conv<1><<<12500, 512, 0, stream>>>(atomb, nbr, idxp, Wb, flags,
                                                stats1, nullptr, gws, nullptr);
        reduce_bn1<<<1, 256, 0, stream>>>(stats1, g1, b1, coef1, flags);
        apply_gated<<<12500, 512, 0, stream>>>(gws, coef1, nsum);
    } else {
        gemm_conv<0><<<12500, 512, 0, stream>>>(atomb, nbr, idxp, Wb, flags,
                                                stats1, nullptr, nullptr, nullptr);
        reduce_bn1<<<1, 256, 0, stream>>>(stats1, g1, b1, coef1, flags);
        gemm_conv<2><<<12500, 512, 0, stream>>>(atomb, nbr, idxp, Wb, flags,
                                                nullptr, coef1, nullptr, nsum);
    }
    bn2_stats<<<512, 256, 0, stream>>>(nsum, stats2);
    reduce_bn2<<<1, 128, 0, stream>>>(stats2, g2, b2, coef2, flags);
    final_out<<<6250, 256, 0, stream>>>(atomb, nsum, coef2, d_out, flags);
}

// Round 2
// 1003.520 us; speedup vs baseline: 1.6106x; 1.6106x over previous
//
#include <hip/hip_runtime.h>

typedef __bf16 bf16x8 __attribute__((ext_vector_type(8)));
typedef __bf16 bf16x4 __attribute__((ext_vector_type(4)));
typedef float  f32x4  __attribute__((ext_vector_type(4)));

#define CIN 320
// LDS layout (bytes): gather 96*256 | edge 96*128 | self 8*256
#define GATHER_OFF 0
#define EDGE_OFF   24576
#define SELF_OFF   36864
#define SMEM_BYTES 38912

// async 16B global->LDS DMA; LDS dest is wave-uniform base + lane*16
#define GLOAD_LDS16(gsrc, ldst)                                              \
    __builtin_amdgcn_global_load_lds(                                        \
        (__attribute__((address_space(1))) void*)(void*)(gsrc),              \
        (__attribute__((address_space(3))) void*)(ldst), 16, 0, 0)

// ---- runtime dtype detection (one wave): flags[0]=fp32 inputs, flags[1]=int64 idx
__global__ void detect_kernel(const unsigned short* __restrict__ atom_h,
                              const unsigned* __restrict__ idx_w, int* __restrict__ flags)
{
    const int lane = threadIdx.x;   // 64
    int f32 = 0;
    for (int i = lane; i < 256; i += 64) {
        const int e = (atom_h[i] >> 7) & 0xFF;   // bf16-exponent view of each halfword
        if (e >= 134) f32 = 1;                   // |x|>=128 impossible for N(0,1) bf16
    }
    const unsigned long long m32 = __ballot(f32);
    const int hi = (idx_w[2 * lane + 1] != 0) ? 1 : 0;
    const unsigned long long mhi = __ballot(hi); // int64 nonneg < 1e5 -> high dwords 0
    if (lane == 0) { flags[0] = m32 ? 1 : 0; flags[1] = mhi ? 0 : 1; }
}

// ---- canonicalize float tensor to bf16 in ws (cvt if fp32, copy if already bf16)
__global__ __launch_bounds__(256) void convert_bf16(const void* __restrict__ src,
    __bf16* __restrict__ dst, long n8, const int* __restrict__ flags)
{
    const long t = (long)blockIdx.x * 256 + threadIdx.x;
    if (t >= n8) return;
    const long i = t * 8;
    if (flags[0]) {
        const float* s = (const float*)src;
        bf16x8 o;
#pragma unroll
        for (int j = 0; j < 8; ++j) o[j] = (__bf16)s[i + j];
        *(bf16x8*)&dst[i] = o;
    } else {
        *(uint4*)&dst[i] = *(const uint4*)((const char*)src + i * 2);
    }
}

// MODE 0 = stats only, 1 = stats + store packed gated fragments, 2 = apply (recompute)
// 512 threads = 8 waves; wave wv owns filter cols [wv*16,wv*16+16) + core cols +128.
template<int MODE>
__global__ __launch_bounds__(512, 4) void gemm_conv(
    const __bf16* __restrict__ atomb, const void* __restrict__ nbrp,
    const void* __restrict__ idxp, const __bf16* __restrict__ Wb,
    const int* __restrict__ flags,
    float* __restrict__ stats1, const float* __restrict__ coef1,
    __bf16* __restrict__ gws, float* __restrict__ nsum)
{
    __shared__ __align__(16) char smem[SMEM_BYTES];

    const int tid = threadIdx.x;
    const int blk = blockIdx.x;
    const long rowbase = (long)blk * 96;
    const int  n0 = blk * 8;
    const int  isf32 = flags[0];
    const int  isi64 = flags[1];

    const int lane = tid & 63;
    const int wv   = tid >> 6;
    const int quad = lane >> 4;
    const int lrow = lane & 15;

    // ---------- async staging ----------
    // self rows deduplicated: 8 rows x 256B, linear (reads broadcast per atom)
    if (wv < 2) {
        const int row = wv * 4 + (lane >> 4);
        GLOAD_LDS16(atomb + (long)(n0 + row) * 128 + (lane & 15) * 8,
                    smem + SELF_OFF + wv * 1024);
    }
    // gather rows: 24 instrs x 4 rows; source pre-swizzled so linear LDS dest
    // yields conflict-free swizzled reads: chunk c of row r lives at (c^(r&7))*16
    long jrow[3]; int grow[3];
#pragma unroll
    for (int i = 0; i < 3; ++i) {
        const int t = wv + i * 8;
        grow[i] = 4 * t + (lane >> 4);
        jrow[i] = isi64 ? (long)((const long long*)idxp)[rowbase + grow[i]]
                        : (long)((const int*)idxp)[rowbase + grow[i]];
    }
#pragma unroll
    for (int i = 0; i < 3; ++i) {
        const int t = wv + i * 8;
        const int chunk = ((lane & 15) << 4) ^ ((grow[i] & 7) << 4);  // byte in 256B row
        GLOAD_LDS16(atomb + jrow[i] * 128 + (chunk >> 1),
                    smem + GATHER_OFF + t * 1024);
    }
    // edge rows (64 feats): bf16 input -> DMA w/ pre-swizzled source; fp32 -> cvt+swizzled write
    if (isf32) {
        const float* nf = (const float*)nbrp;
#pragma unroll
        for (int rnd = 0; rnd < 2; ++rnd) {
            const int task = tid + rnd * 512;
            if (task < 768) {
                const int c = task & 7, row = task >> 3;
                const float* sp = &nf[(rowbase + row) * 64 + c * 8];
                f32x4 v0 = *(const f32x4*)sp;
                f32x4 v1 = *(const f32x4*)(sp + 4);
                bf16x8 o;
#pragma unroll
                for (int j = 0; j < 4; ++j) { o[j] = (__bf16)v0[j]; o[j + 4] = (__bf16)v1[j]; }
                *(bf16x8*)(smem + EDGE_OFF + row * 128 + ((c ^ (row & 7)) << 4)) = o;
            }
        }
    } else {
        const __bf16* nb = (const __bf16*)nbrp;
#pragma unroll
        for (int i = 0; i < 2; ++i) {
            const int t = wv + i * 8;
            if (t < 12) {
                const int row = 8 * t + (lane >> 3);
                const int c = lane & 7;
                const int chunk = (c << 4) ^ ((row & 7) << 4);
                GLOAD_LDS16(nb + (rowbase + row) * 64 + (chunk >> 1),
                            smem + EDGE_OFF + t * 1024);
            }
        }
    }
    __syncthreads();

    // ---------- MFMA ----------
    const int cF = wv * 16 + lrow;                       // 0..127
    const __bf16* wpF = Wb + (long)cF * CIN + quad * 8;
    const __bf16* wpC = Wb + (long)(128 + cF) * CIN + quad * 8;

    int arow[6], aatom[6];
#pragma unroll
    for (int rt = 0; rt < 6; ++rt) {
        arow[rt]  = rt * 16 + lrow;
        aatom[rt] = (arow[rt] * 171) >> 11;              // == row/12 for row<96
    }

    f32x4 acc[6][2] = {};
    bf16x8 bF = *(const bf16x8*)wpF;
    bf16x8 bC = *(const bf16x8*)wpC;
    bf16x8 bFn, bCn;

#pragma unroll
    for (int kk = 0; kk < 10; ++kk) {
        if (kk < 9) {
            bFn = *(const bf16x8*)(wpF + (kk + 1) * 32);
            bCn = *(const bf16x8*)(wpC + (kk + 1) * 32);
        }
#pragma unroll
        for (int rt = 0; rt < 6; ++rt) {
            int addr;
            if (kk < 4)
                addr = SELF_OFF + aatom[rt] * 256 + kk * 64 + quad * 16;
            else if (kk < 8)
                addr = GATHER_OFF + arow[rt] * 256 + ((((kk - 4) * 4 + quad) ^ (arow[rt] & 7)) << 4);
            else
                addr = EDGE_OFF + arow[rt] * 128 + ((((kk - 8) * 4 + quad) ^ (arow[rt] & 7)) << 4);
            const bf16x8 afrag = *(const bf16x8*)(smem + addr);
            acc[rt][0] = __builtin_amdgcn_mfma_f32_16x16x32_bf16(afrag, bF, acc[rt][0], 0, 0, 0);
            acc[rt][1] = __builtin_amdgcn_mfma_f32_16x16x32_bf16(afrag, bC, acc[rt][1], 0, 0, 0);
        }
        if (kk < 9) { bF = bFn; bC = bCn; }
    }

    if (MODE <= 1) {
        float* st = stats1 + (blk & 63) * 512;
#pragma unroll
        for (int p = 0; p < 2; ++p) {
            float s = 0.f, ss = 0.f;
#pragma unroll
            for (int rt = 0; rt < 6; ++rt)
#pragma unroll
                for (int r = 0; r < 4; ++r) {
                    const float v = acc[rt][p][r];
                    s += v; ss += v * v;
                }
            s += __shfl_xor(s, 16); ss += __shfl_xor(ss, 16);
            s += __shfl_xor(s, 32); ss += __shfl_xor(ss, 32);
            if (quad == 0) {
                atomicAdd(&st[p * 128 + cF], s);
                atomicAdd(&st[256 + p * 128 + cF], ss);
            }
        }
        if (MODE == 1) {
            // store fragments directly: word = pack(bf16 filt, bf16 core)
            // layout: [blk][rt(6)][tid(512)][16B]  -> 48KB/block, fully coalesced
            char* dst = (char*)gws + (long)blk * 49152;
#pragma unroll
            for (int rt = 0; rt < 6; ++rt) {
                unsigned u[4];
#pragma unroll
                for (int r = 0; r < 4; ++r) {
                    const unsigned short fb =
                        __builtin_bit_cast(unsigned short, (__bf16)acc[rt][0][r]);
                    const unsigned short cb =
                        __builtin_bit_cast(unsigned short, (__bf16)acc[rt][1][r]);
                    u[r] = (unsigned)fb | ((unsigned)cb << 16);
                }
                *(uint4*)(dst + rt * 8192 + tid * 16) = *(const uint4*)u;
            }
        }
    } else {
        // MODE 2: bn1 affine + sigmoid(filter)*relu(core), reduce over m in LDS
        __syncthreads();                      // done reading staged A
        float* sumbuf = (float*)smem;         // 8 atoms x 128 ch
        sumbuf[tid] = 0.f; sumbuf[tid + 512] = 0.f;
        __syncthreads();
        const float aF = coef1[cF],       bFc = coef1[256 + cF];
        const float aC = coef1[128 + cF], bCc = coef1[384 + cF];
#pragma unroll
        for (int rt = 0; rt < 6; ++rt)
#pragma unroll
            for (int r = 0; r < 4; ++r) {
                const int row  = rt * 16 + quad * 4 + r;
                const int atom = (row * 171) >> 11;
                const float gF = aF * acc[rt][0][r] + bFc;
                const float gC = aC * acc[rt][1][r] + bCc;
                const float val = (1.f / (1.f + __expf(-gF))) * fmaxf(gC, 0.f);
                atomicAdd(&sumbuf[atom * 128 + cF], val);
            }
        __syncthreads();
        nsum[(long)n0 * 128 + tid]       = sumbuf[tid];
        nsum[(long)n0 * 128 + 512 + tid] = sumbuf[tid + 512];
    }
}

__global__ void reduce_bn1(const float* __restrict__ stats1, const void* __restrict__ gamma,
                           const void* __restrict__ beta, float* __restrict__ coef1,
                           const int* __restrict__ flags)
{
    const int c = threadIdx.x;  // 256
    const int isf32 = flags[0];
    float s = 0.f, ss = 0.f;
    for (int b = 0; b < 64; ++b) { s += stats1[b * 512 + c]; ss += stats1[b * 512 + 256 + c]; }
    const float inv  = 1.f / 1200000.f;
    const float mean = s * inv;
    const float var  = ss * inv - mean * mean;
    const float g  = isf32 ? ((const float*)gamma)[c] : (float)((const __bf16*)gamma)[c];
    const float bb = isf32 ? ((const float*)beta)[c]  : (float)((const __bf16*)beta)[c];
    const float A = g * rsqrtf(var + 1e-5f);
    coef1[c]       = A;
    coef1[256 + c] = bb - A * mean;   // linear bias b cancels in BN1 (mean-subtracted)
}

// Path A: read fragment-layout gated; each thread owns (atom, channel) pairs,
// m-reduction entirely in registers. Zero LDS, zero atomics, fully coalesced.
// Fragment inverse map: word(row=rt*16+quad*4+r, cF=wv*16+lrow) is at byte
//   blk*49152 + rt*8192 + wv*1024 + quad*256 + lrow*16 + r*4.
// Atom a's 12 rows = 3 aligned row-quads starting at 12a, 12a+4, 12a+8.
__global__ __launch_bounds__(512) void apply_gated(const __bf16* __restrict__ g,
    const float* __restrict__ coef1, float* __restrict__ nsum)
{
    const int tid   = threadIdx.x;
    const int blk   = blockIdx.x;
    const int lrow  = tid & 15;
    const int wv_ch = (tid >> 4) & 7;
    const int apair = tid >> 7;              // 0..3 -> atoms {apair, apair+4}
    const int cF    = wv_ch * 16 + lrow;

    const float aF = coef1[cF],       bF = coef1[256 + cF];
    const float aC = coef1[128 + cF], bC = coef1[384 + cF];
    const char* src = (const char*)g + (long)blk * 49152 + wv_ch * 1024 + lrow * 16;

    float out[2];
#pragma unroll
    for (int p = 0; p < 2; ++p) {
        const int a = apair + p * 4;
        float s = 0.f;
#pragma unroll
        for (int u = 0; u < 3; ++u) {
            const int rowstart = a * 12 + u * 4;
            const int rt   = rowstart >> 4;
            const int quad = (rowstart >> 2) & 3;
            const uint4 w = *(const uint4*)(src + rt * 8192 + quad * 256);
            const unsigned uw[4] = {w.x, w.y, w.z, w.w};
#pragma unroll
            for (int r = 0; r < 4; ++r) {
                const float gF = aF * (float)__builtin_bit_cast(__bf16, (unsigned short)(uw[r] & 0xFFFFu)) + bF;
                const float gC = aC * (float)__builtin_bit_cast(__bf16, (unsigned short)(uw[r] >> 16)) + bC;
                s += (1.f / (1.f + __expf(-gF))) * fmaxf(gC, 0.f);
            }
        }
        out[p] = s;
    }
    const long n0 = (long)blk * 8;
#pragma unroll
    for (int p = 0; p < 2; ++p)
        nsum[(n0 + apair + p * 4) * 128 + cF] = out[p];
}

__global__ __launch_bounds__(256) void bn2_stats(const float* __restrict__ nsum,
                                                 float* __restrict__ stats2)
{
    __shared__ float ls[256], lss[256];
    const int tid = threadIdx.x;
    float s = 0.f, ss = 0.f;
    const long stride = (long)gridDim.x * 256;   // multiple of 128
    for (long i = (long)blockIdx.x * 256 + tid; i < 12800000L; i += stride) {
        const float v = nsum[i]; s += v; ss += v * v;
    }
    ls[tid] = s; lss[tid] = ss;
    __syncthreads();
    if (tid < 128) {
        atomicAdd(&stats2[tid],       ls[tid] + ls[tid + 128]);
        atomicAdd(&stats2[128 + tid], lss[tid] + lss[tid + 128]);
    }
}

__global__ void reduce_bn2(const float* __restrict__ stats2, const void* __restrict__ gamma,
                           const void* __restrict__ beta, float* __restrict__ coef2,
                           const int* __restrict__ flags)
{
    const int c = threadIdx.x;  // 128
    const int isf32 = flags[0];
    const float inv  = 1.f / 100000.f;
    const float mean = stats2[c] * inv;
    const float var  = stats2[128 + c] * inv - mean * mean;
    const float g  = isf32 ? ((const float*)gamma)[c] : (float)((const __bf16*)gamma)[c];
    const float bb = isf32 ? ((const float*)beta)[c]  : (float)((const __bf16*)beta)[c];
    const float A = g * rsqrtf(var + 1e-5f);
    coef2[c]       = A;
    coef2[128 + c] = bb - A * mean;
}

__global__ __launch_bounds__(256) void final_out(const __bf16* __restrict__ atomb,
    const float* __restrict__ nsum, const float* __restrict__ coef2,
    void* __restrict__ outp, const int* __restrict__ flags)
{
    const long i = ((long)blockIdx.x * 256 + threadIdx.x) * 8;   // 6250*256*8 = 12.8M exact
    const int f0 = (int)(i & 127);
    bf16x8 a  = *(const bf16x8*)&atomb[i];
    f32x4  u0 = *(const f32x4*)&nsum[i];
    f32x4  u1 = *(const f32x4*)&nsum[i + 4];
    float v[8];
#pragma unroll
    for (int j = 0; j < 8; ++j) {
        const float A  = coef2[f0 + j];
        const float B  = coef2[128 + f0 + j];
        const float ns = (j < 4) ? u0[j] : u1[j - 4];
        v[j] = fmaxf((float)a[j] + A * ns + B, 0.f);
    }
    if (flags[0]) {
        float* o = (float*)outp;
        f32x4 w0 = {v[0], v[1], v[2], v[3]}, w1 = {v[4], v[5], v[6], v[7]};
        *(f32x4*)&o[i]     = w0;
        *(f32x4*)&o[i + 4] = w1;
    } else {
        __bf16* o = (__bf16*)outp;
        bf16x8 w;
#pragma unroll
        for (int j = 0; j < 8; ++j) w[j] = (__bf16)v[j];
        *(bf16x8*)&o[i] = w;
    }
}

extern "C" void kernel_launch(void* const* d_in, const int* in_sizes, int n_in,
                              void* d_out, int out_size, void* d_ws, size_t ws_size,
                              hipStream_t stream)
{
    const void* atom = d_in[0];
    const void* nbr  = d_in[1];
    const void* idxp = d_in[2];
    const void* W    = d_in[3];
    // d_in[4] = linear bias: cancels exactly inside BN1, unused
    const void* g1   = d_in[5];
    const void* b1   = d_in[6];
    const void* g2   = d_in[7];
    const void* b2   = d_in[8];

    char* ws = (char*)d_ws;
    int*    flags  = (int*)ws;                       // 16 B
    float*  stats1 = (float*)(ws + 1024);            // 64*512*4 = 131072
    float*  coef1  = (float*)(ws + 132096);          // 2048
    float*  stats2 = (float*)(ws + 134144);          // 1024
    float*  coef2  = (float*)(ws + 135168);          // 1024
    __bf16* atomb  = (__bf16*)(ws + 136192);         // 12.8M bf16 = 25,600,000
    __bf16* Wb     = (__bf16*)(ws + 25736192);       // 81920 bf16 = 163,840
    float*  nsum   = (float*)(ws + 25900032);        // 100000*128*4 = 51,200,000
    __bf16* gws    = (__bf16*)(ws + 77100032);       // 12500*49152 = 614,400,000

    const size_t need_big = 77100032UL + 614400000UL;

    hipMemsetAsync(ws, 0, 136192, stream);           // zero flags + stats (ws poisoned 0xAA)
    detect_kernel<<<1, 64, 0, stream>>>((const unsigned short*)atom, (const unsigned*)idxp, flags);
    convert_bf16<<<6250, 256, 0, stream>>>(atom, atomb, 1600000L, flags);
    convert_bf16<<<40, 256, 0, stream>>>(W, Wb, 10240L, flags);

    if (ws_size >= need_big) {
        gemm_conv<1><<<12500, 512, 0, stream>>>(atomb, nbr, idxp, Wb, flags,
                                                stats1, nullptr, gws, nullptr);
        reduce_bn1<<<1, 256, 0, stream>>>(stats1, g1, b1, coef1, flags);
        apply_gated<<<12500, 512, 0, stream>>>(gws, coef1, nsum);
    } else {
        gemm_conv<0><<<12500, 512, 0, stream>>>(atomb, nbr, idxp, Wb, flags,
                                                stats1, nullptr, nullptr, nullptr);
        reduce_bn1<<<1, 256, 0, stream>>>(stats1, g1, b1, coef1, flags);
        gemm_conv<2><<<12500, 512, 0, stream>>>(atomb, nbr, idxp, Wb, flags,
                                                nullptr, coef1, nullptr, nsum);
    }
    bn2_stats<<<512, 256, 0, stream>>>(nsum, stats2);
    reduce_bn2<<<1, 128, 0, stream>>>(stats2, g2, b2, coef2, flags);
    final_out<<<6250, 256, 0, stream>>>(atomb, nsum, coef2, d_out, flags);
}